// Round 9
// baseline (308.604 us; speedup 1.0000x reference)
//
#include <hip/hip_runtime.h>
#include <hip/hip_bf16.h>

// ---------------------------------------------------------------------------
// MultiHeadAttention forward on MI355X (gfx950). B=2,S=2048,D=768,H=12,Dh=64.
// Masks scale by +1e-9 (numeric no-op) -> full non-causal softmax; dropped.
//
// Round 9:
//  * attn: 32q/wave AND z=4 key-split (grid 1536 = 6 blocks/CU, 16 KB tiles,
//    single-buffered -- r8 showed dbuf is neutral; idle is phase lockstep).
//    Denominator on VALU (l_part + shfl), off the busier MFMA pipe.
//  * k_comb deleted: proj A-staging fuses partial-combine + 1/l scaling
//    (BK=64 k-tiles align exactly with 64-wide heads -> per-iter scalar inv).
// ---------------------------------------------------------------------------

typedef __attribute__((ext_vector_type(8))) short short8;
typedef __attribute__((ext_vector_type(4))) float float4v;
typedef __attribute__((ext_vector_type(8))) _Float16 half8;
typedef __attribute__((ext_vector_type(4))) _Float16 half4;
typedef __attribute__((ext_vector_type(4))) unsigned short ushort4v;
typedef __attribute__((ext_vector_type(8))) unsigned short ushort8v;

__device__ __forceinline__ void async_copy16(const void* g, void* l) {
  __builtin_amdgcn_global_load_lds(
      (const __attribute__((address_space(1))) void*)g,
      (__attribute__((address_space(3))) void*)l, 16, 0, 0);
}

__device__ __forceinline__ float fast_exp2(float x) {
#if __has_builtin(__builtin_amdgcn_exp2f)
  return __builtin_amdgcn_exp2f(x);
#else
  return exp2f(x);
#endif
}

__device__ __forceinline__ unsigned short f2bf(float v) {
  __hip_bfloat16 h = __float2bfloat16(v);
  unsigned short u;
  __builtin_memcpy(&u, &h, 2);
  return u;
}

__device__ __forceinline__ float bf2f(unsigned short u) {
  unsigned int x = ((unsigned int)u) << 16;
  float f;
  __builtin_memcpy(&f, &x, 4);
  return f;
}

#define LOG2E_8 0.18033688011112042f  // log2(e)/8, folded into Q

// ---- fused prep: x f32->bf16 cast; w_qkv, w_proj transpose->bf16 -----------
__global__ __launch_bounds__(256) void k_prep(
    const float* __restrict__ x, unsigned short* __restrict__ xb,
    const float* __restrict__ wqkv, __hip_bfloat16* __restrict__ wqkvT,
    const float* __restrict__ wproj, __hip_bfloat16* __restrict__ wprojT) {
  __shared__ float tile[32][33];
  const int bid = blockIdx.x, tid = threadIdx.x;
  if (bid < 3072) {  // cast: 4096*768 floats, 4/thread
    int i = bid * 256 + tid;
    float4v v = ((const float4v*)x)[i];
    ushort4v o;
#pragma unroll
    for (int r = 0; r < 4; r++) o[r] = f2bf(v[r]);
    ((ushort4v*)xb)[i] = o;
    return;
  }
  const float* w;
  __hip_bfloat16* wt;
  int N, bx, by;
  if (bid < 4800) {
    int t = bid - 3072; w = wqkv; wt = wqkvT; N = 2304; bx = t % 72; by = t / 72;
  } else {
    int t = bid - 4800; w = wproj; wt = wprojT; N = 768; bx = t % 24; by = t / 24;
  }
  const int n0 = bx * 32, k0 = by * 32;
  const int r = tid >> 5, c = tid & 31;
#pragma unroll
  for (int rr = 0; rr < 32; rr += 8)
    tile[rr + r][c] = w[(long long)(k0 + rr + r) * N + n0 + c];
  __syncthreads();
#pragma unroll
  for (int rr = 0; rr < 32; rr += 8)
    wt[(long long)(n0 + rr + r) * 768 + k0 + c] = __float2bfloat16(tile[c][rr + r]);
}

// ---- bf16 GEMM, BK=64, K=768 (12 iters), conflict-free XOR swizzle ---------
// EPI==0: 128x96 tile; A async from Xb; scatter Q(prescaled),K,V^T f16 +bias.
// EPI==1: 64x64 tile; A staged from 4 bf16 attention partials + 1/l scaling
//         (A param = partials base, Sm = denominators); out f32 = acc + bias.
template <int EPI>
__global__ __launch_bounds__(256) void k_gemm_bt(
    const __hip_bfloat16* __restrict__ A, const __hip_bfloat16* __restrict__ Bt,
    const float* __restrict__ bias, const float* __restrict__ Sm,
    float* __restrict__ outF,
    _Float16* __restrict__ Qb, _Float16* __restrict__ Kb,
    _Float16* __restrict__ VT) {
  constexpr int BM = (EPI == 0) ? 128 : 64;
  constexpr int BN = (EPI == 0) ? 96 : 64;
  constexpr int MT = BM / 32;  // 16-tiles per wave (m)
  constexpr int NT = BN / 32;  // 16-tiles per wave (n)
  __shared__ __align__(16) __hip_bfloat16 At[BM * 64];
  __shared__ __align__(16) __hip_bfloat16 Btl[BN * 64];
  const int tid = threadIdx.x;
  const int w = tid >> 6, l = tid & 63;
  const int quad = l >> 4, lane16 = l & 15;
  const int m0 = blockIdx.x * BM, n0 = blockIdx.y * BN;

  float4v acc[MT][NT];
#pragma unroll
  for (int i = 0; i < MT; i++)
#pragma unroll
    for (int j = 0; j < NT; j++) acc[i][j] = float4v{0.f, 0.f, 0.f, 0.f};

  const int srow = tid >> 3;
  const int gsrc = (tid & 7) ^ (srow & 7);  // source granule (xor-swizzled)
  const __hip_bfloat16* Asrc = A + (long long)(m0 + srow) * 768 + gsrc * 8;
  const __hip_bfloat16* Bsrc = Bt + (long long)(n0 + srow) * 768 + gsrc * 8;
  __hip_bfloat16* Adst = At + tid * 8;
  __hip_bfloat16* Bdst = Btl + tid * 8;

  const int wr = (w >> 1) * (BM / 2), wc = (w & 1) * (BN / 2);
  const int swz = lane16 & 7;

  for (int kt = 0; kt < 12; kt++) {
    const int k0 = kt * 64;
    __syncthreads();
    if (EPI == 0) {
#pragma unroll
      for (int c = 0; c < BM / 32; c++)
        async_copy16(Asrc + (long long)c * 32 * 768 + k0, Adst + c * 2048);
    } else {
      // fused combine: A = (sum_z Op_z) * (1 / sum_z l_z); head index == kt
#pragma unroll
      for (int c = 0; c < BM / 32; c++) {
        const int m = m0 + c * 32 + srow;
        const int bh = (m >> 11) * 12 + kt;
        const int si = m & 2047;
        float den = Sm[bh * 2048 + si] + Sm[49152 + bh * 2048 + si] +
                    Sm[2 * 49152 + bh * 2048 + si] + Sm[3 * 49152 + bh * 2048 + si];
        const float inv = __builtin_amdgcn_rcpf(den);
        const unsigned short* ap =
            (const unsigned short*)A + (long long)m * 768 + k0 + gsrc * 8;
        ushort8v p0 = *(const ushort8v*)(ap);
        ushort8v p1 = *(const ushort8v*)(ap + 4096ull * 768);
        ushort8v p2 = *(const ushort8v*)(ap + 2ull * 4096 * 768);
        ushort8v p3 = *(const ushort8v*)(ap + 3ull * 4096 * 768);
        ushort8v o;
#pragma unroll
        for (int e = 0; e < 8; e++)
          o[e] = f2bf((bf2f(p0[e]) + bf2f(p1[e]) + bf2f(p2[e]) + bf2f(p3[e])) * inv);
        *(ushort8v*)((unsigned short*)At + c * 2048 + tid * 8) = o;
      }
    }
#pragma unroll
    for (int c = 0; c < BN / 32; c++)
      async_copy16(Bsrc + (long long)c * 32 * 768 + k0, Bdst + c * 2048);
    __syncthreads();
#pragma unroll
    for (int h = 0; h < 2; h++) {
      short8 af[MT], bf[NT];
#pragma unroll
      for (int t = 0; t < MT; t++)
        af[t] = *(const short8*)(At + (wr + t * 16 + lane16) * 64 +
                                 (((h * 4 + quad) ^ swz) * 8));
#pragma unroll
      for (int t = 0; t < NT; t++)
        bf[t] = *(const short8*)(Btl + (wc + t * 16 + lane16) * 64 +
                                 (((h * 4 + quad) ^ swz) * 8));
#pragma unroll
      for (int i = 0; i < MT; i++)
#pragma unroll
        for (int j = 0; j < NT; j++)
          acc[i][j] = __builtin_amdgcn_mfma_f32_16x16x32_bf16(af[i], bf[j], acc[i][j], 0, 0, 0);
    }
  }

  // epilogue: C/D layout col=lane16, row=quad*4+reg
#pragma unroll
  for (int i = 0; i < MT; i++) {
    const int mbase = m0 + wr + i * 16 + quad * 4;
#pragma unroll
    for (int j = 0; j < NT; j++) {
      const int n = n0 + wc + j * 16 + lane16;
      const float bv = bias[n];
      if (EPI == 0) {
        const int which = n / 768;  // uniform across the 16-lane tile
        const int rr = n - which * 768;
        const int hh = rr >> 6, dh = rr & 63;
        const float scale = (which == 0) ? LOG2E_8 : 1.0f;
#pragma unroll
        for (int r = 0; r < 4; r++) {
          const int mm = mbase + r;
          const int b = mm >> 11, s = mm & 2047;
          _Float16 val = (_Float16)((acc[i][j][r] + bv) * scale);
          if (which == 0)
            Qb[((long long)(b * 12 + hh) * 2048 + s) * 64 + dh] = val;
          else if (which == 1)
            Kb[((long long)(b * 12 + hh) * 2048 + s) * 64 + dh] = val;
          else
            VT[((long long)(b * 12 + hh) * 64 + dh) * 2048 + s] = val;
        }
      } else {
#pragma unroll
        for (int r = 0; r < 4; r++)
          outF[(long long)(mbase + r) * 768 + n] = acc[i][j][r] + bv;
      }
    }
  }
}

// ---- attention: 32 q/wave, f16, S^T form, key-split x4, 64-key tiles -------
// grid (S/128, B*H, 4). 4 waves x 32 q = 128 q-rows; 512 keys each (8 iters).
// Single-buffered (dbuf measured neutral); VALU denominator; bf16 partials.
__global__ __launch_bounds__(256, 6) void k_attn(
    const _Float16* __restrict__ Qb, const _Float16* __restrict__ Kb,
    const _Float16* __restrict__ VT, unsigned short* __restrict__ Op,
    float* __restrict__ Sm) {
  __shared__ __align__(16) _Float16 Kl[64 * 64];  // [key][dh], slot g^(r&7)
  __shared__ __align__(16) _Float16 Vl[64 * 64];  // [dh][key], slot g^(r&7)
  const int tid = threadIdx.x, w = tid >> 6, l = tid & 63;
  const int quad = l >> 4, lane16 = l & 15;
  const int bh = blockIdx.y, z = blockIdx.z;
  const int q0w = blockIdx.x * 128 + w * 32;
  const _Float16* Qp = Qb + (long long)bh * 2048 * 64;
  const _Float16* Kp = Kb + (long long)bh * 2048 * 64;
  const _Float16* Vp = VT + (long long)bh * 64 * 2048;

  // Q as B-frags of S^T: B[n=q=lane16][k=dh=quad*8+j], 2 q-groups x 2 k-halves
  half8 qf[2][2];
#pragma unroll
  for (int g = 0; g < 2; g++)
#pragma unroll
    for (int hh = 0; hh < 2; hh++)
      qf[g][hh] = *(const half8*)(Qp + (q0w + g * 16 + lane16) * 64 + hh * 32 + quad * 8);

  float4v o_acc[2][4];  // O^T[dh=dt*16+quad*4+r][q(group g)=lane16]
#pragma unroll
  for (int g = 0; g < 2; g++)
#pragma unroll
    for (int t = 0; t < 4; t++) o_acc[g][t] = float4v{0.f, 0.f, 0.f, 0.f};
  float l_part[2] = {0.f, 0.f};

  // staging: rows of 8 granules; thread t -> row t>>3 (+32 on 2nd call),
  // source granule (t&7)^(row&7), dest slot t&7.
  const int srow = tid >> 3, sgr = (tid & 7) ^ ((tid >> 3) & 7);
  const _Float16* Ksrc = Kp + (long long)(z * 512 + srow) * 64 + sgr * 8;
  const _Float16* Vsrc = Vp + (long long)srow * 2048 + z * 512 + sgr * 8;
  _Float16* Kdst = Kl + tid * 8;
  _Float16* Vdst = Vl + tid * 8;
  const int swz = lane16 & 7;

  for (int kt = 0; kt < 8; kt++) {
    __syncthreads();
#pragma unroll
    for (int c = 0; c < 2; c++) {
      async_copy16(Ksrc + kt * 4096 + (long long)c * 32 * 64, Kdst + c * 2048);
      async_copy16(Vsrc + kt * 64 + (long long)c * 32 * 2048, Vdst + c * 2048);
    }
    __syncthreads();

    // S^T = K Q^T : A = K-frag [m=key][k=dh]; each load feeds both q-groups
    float4v s[2][4];
#pragma unroll
    for (int kb = 0; kb < 4; kb++) {
      const _Float16* kr = Kl + (kb * 16 + lane16) * 64;
      half8 kf0 = *(const half8*)(kr + ((quad ^ swz) * 8));
      half8 kf1 = *(const half8*)(kr + (((4 + quad) ^ swz) * 8));
#pragma unroll
      for (int g = 0; g < 2; g++) {
        float4v zz = float4v{0.f, 0.f, 0.f, 0.f};
        zz = __builtin_amdgcn_mfma_f32_16x16x32_f16(kf0, qf[g][0], zz, 0, 0, 0);
        s[g][kb] = __builtin_amdgcn_mfma_f32_16x16x32_f16(kf1, qf[g][1], zz, 0, 0, 0);
      }
    }
    // p = exp2(s'); P^T packed (pk cvt) as K=16 B-frags; denom on VALU
    half4 pf[2][4];
#pragma unroll
    for (int g = 0; g < 2; g++)
#pragma unroll
      for (int kb = 0; kb < 4; kb++) {
        float p0 = fast_exp2(s[g][kb][0]);
        float p1 = fast_exp2(s[g][kb][1]);
        float p2 = fast_exp2(s[g][kb][2]);
        float p3 = fast_exp2(s[g][kb][3]);
        l_part[g] += (p0 + p1) + (p2 + p3);
        auto lo = __builtin_amdgcn_cvt_pkrtz(p0, p1);
        auto hi = __builtin_amdgcn_cvt_pkrtz(p2, p3);
        pf[g][kb] = half4{static_cast<_Float16>(lo[0]), static_cast<_Float16>(lo[1]),
                          static_cast<_Float16>(hi[0]), static_cast<_Float16>(hi[1])};
      }
    // O^T += V^T P^T : A = V-frag [m=dh][k=key]; each load feeds both groups
#pragma unroll
    for (int dt = 0; dt < 4; dt++) {
      const _Float16* vr = Vl + (dt * 16 + lane16) * 64;
#pragma unroll
      for (int kb = 0; kb < 4; kb++) {
        const int g16 = kb * 2 + (quad >> 1);
        half4 vf = *(const half4*)(vr + ((g16 ^ swz) * 8) + (quad & 1) * 4);
#pragma unroll
        for (int g = 0; g < 2; g++)
          o_acc[g][dt] = __builtin_amdgcn_mfma_f32_16x16x16f16(vf, pf[g][kb], o_acc[g][dt], 0, 0, 0);
      }
    }
  }
  // denominator: sum the 16 keys/lane partials across quads (each q=lane16)
  const int b = bh / 12, hd = bh - (bh / 12) * 12;
#pragma unroll
  for (int g = 0; g < 2; g++) {
    float t = l_part[g];
    t += __shfl_xor(t, 16, 64);
    t += __shfl_xor(t, 32, 64);
    const int qrow = q0w + g * 16 + lane16;
    unsigned short* op = Op + (long long)z * 4096 * 768 +
                         ((long long)b * 2048 + qrow) * 768 + hd * 64 + quad * 4;
#pragma unroll
    for (int dt = 0; dt < 4; dt++) {
      ushort4v cv;
#pragma unroll
      for (int r = 0; r < 4; r++) cv[r] = f2bf(o_acc[g][dt][r]);
      *(ushort4v*)(op + dt * 16) = cv;
    }
    if (quad == 0)
      Sm[(long long)z * 49152 + bh * 2048 + qrow] = t;
  }
}

extern "C" void kernel_launch(void* const* d_in, const int* in_sizes, int n_in,
                              void* d_out, int out_size, void* d_ws, size_t ws_size,
                              hipStream_t stream) {
  const float* x = (const float*)d_in[0];
  // d_in[1] attention_mask: masks scaled by +1e-9 -> no-op, dropped
  const float* w_qkv = (const float*)d_in[2];
  const float* b_qkv = (const float*)d_in[3];
  const float* w_proj = (const float*)d_in[4];
  const float* b_proj = (const float*)d_in[5];
  float* out = (float*)d_out;

  char* ws = (char*)d_ws;
  size_t off = 0;
  auto alloc = [&](size_t bytes) {
    void* p = ws + off;
    off += (bytes + 255) & ~(size_t)255;
    return p;
  };
  __hip_bfloat16* Xb = (__hip_bfloat16*)alloc(4096ull * 768 * 2);      // 6.3 MB
  __hip_bfloat16* WqkvT = (__hip_bfloat16*)alloc(2304ull * 768 * 2);   // 3.5 MB
  __hip_bfloat16* WprojT = (__hip_bfloat16*)alloc(768ull * 768 * 2);   // 1.2 MB
  _Float16* Qb = (_Float16*)alloc(3145728ull * 2);                     // 6.3 MB
  _Float16* Kb = (_Float16*)alloc(3145728ull * 2);                     // 6.3 MB
  _Float16* VT = (_Float16*)alloc(3145728ull * 2);                     // 6.3 MB
  unsigned short* Opb = (unsigned short*)alloc(4ull * 4096 * 768 * 2); // 25.2 MB
  float* Sm = (float*)alloc(4ull * 24 * 2048 * 4);                     // 0.8 MB

  k_prep<<<5376, 256, 0, stream>>>(x, (unsigned short*)Xb, w_qkv, WqkvT,
                                   w_proj, WprojT);
  k_gemm_bt<0><<<dim3(32, 24), 256, 0, stream>>>(Xb, WqkvT, b_qkv, nullptr,
                                                 nullptr, Qb, Kb, VT);
  k_attn<<<dim3(16, 24, 4), 256, 0, stream>>>(Qb, Kb, VT, Opb, Sm);
  k_gemm_bt<1><<<dim3(64, 12), 256, 0, stream>>>((const __hip_bfloat16*)Opb,
                                                 WprojT, b_proj, Sm, out,
                                                 nullptr, nullptr, nullptr);
}

// Round 10
// 171.481 us; speedup vs baseline: 1.7996x; 1.7996x over previous
//
#include <hip/hip_runtime.h>
#include <hip/hip_bf16.h>

// ---------------------------------------------------------------------------
// MultiHeadAttention forward on MI355X (gfx950). B=2,S=2048,D=768,H=12,Dh=64.
// Masks scale by +1e-9 (numeric no-op) -> full non-causal softmax; dropped.
//
// Round 10: recover from R9's launch_bounds(256,6) spill disaster (VGPR cap
// 40 < ~100 live -> 800 MB scratch traffic). Consistent point:
//  * attn: 32q/wave, z=4 key-split, __launch_bounds__(256,4) (128 VGPR budget,
//    4 blocks/CU), 128-key tiles (32 KB LDS; barriers halved 8->4). Inner loop
//    per-16-key-block to keep s/pf liveness at 8 regs. Ones-MFMA denominator.
//  * proj keeps R9's fused partial-combine (verified correct); no k_comb.
// ---------------------------------------------------------------------------

typedef __attribute__((ext_vector_type(8))) short short8;
typedef __attribute__((ext_vector_type(4))) float float4v;
typedef __attribute__((ext_vector_type(8))) _Float16 half8;
typedef __attribute__((ext_vector_type(4))) _Float16 half4;
typedef __attribute__((ext_vector_type(4))) unsigned short ushort4v;
typedef __attribute__((ext_vector_type(8))) unsigned short ushort8v;

__device__ __forceinline__ void async_copy16(const void* g, void* l) {
  __builtin_amdgcn_global_load_lds(
      (const __attribute__((address_space(1))) void*)g,
      (__attribute__((address_space(3))) void*)l, 16, 0, 0);
}

__device__ __forceinline__ float fast_exp2(float x) {
#if __has_builtin(__builtin_amdgcn_exp2f)
  return __builtin_amdgcn_exp2f(x);
#else
  return exp2f(x);
#endif
}

__device__ __forceinline__ unsigned short f2bf(float v) {
  __hip_bfloat16 h = __float2bfloat16(v);
  unsigned short u;
  __builtin_memcpy(&u, &h, 2);
  return u;
}

__device__ __forceinline__ float bf2f(unsigned short u) {
  unsigned int x = ((unsigned int)u) << 16;
  float f;
  __builtin_memcpy(&f, &x, 4);
  return f;
}

#define LOG2E_8 0.18033688011112042f  // log2(e)/8, folded into Q

// ---- fused prep: x f32->bf16 cast; w_qkv, w_proj transpose->bf16 -----------
__global__ __launch_bounds__(256) void k_prep(
    const float* __restrict__ x, unsigned short* __restrict__ xb,
    const float* __restrict__ wqkv, __hip_bfloat16* __restrict__ wqkvT,
    const float* __restrict__ wproj, __hip_bfloat16* __restrict__ wprojT) {
  __shared__ float tile[32][33];
  const int bid = blockIdx.x, tid = threadIdx.x;
  if (bid < 3072) {  // cast: 4096*768 floats, 4/thread
    int i = bid * 256 + tid;
    float4v v = ((const float4v*)x)[i];
    ushort4v o;
#pragma unroll
    for (int r = 0; r < 4; r++) o[r] = f2bf(v[r]);
    ((ushort4v*)xb)[i] = o;
    return;
  }
  const float* w;
  __hip_bfloat16* wt;
  int N, bx, by;
  if (bid < 4800) {
    int t = bid - 3072; w = wqkv; wt = wqkvT; N = 2304; bx = t % 72; by = t / 72;
  } else {
    int t = bid - 4800; w = wproj; wt = wprojT; N = 768; bx = t % 24; by = t / 24;
  }
  const int n0 = bx * 32, k0 = by * 32;
  const int r = tid >> 5, c = tid & 31;
#pragma unroll
  for (int rr = 0; rr < 32; rr += 8)
    tile[rr + r][c] = w[(long long)(k0 + rr + r) * N + n0 + c];
  __syncthreads();
#pragma unroll
  for (int rr = 0; rr < 32; rr += 8)
    wt[(long long)(n0 + rr + r) * 768 + k0 + c] = __float2bfloat16(tile[c][rr + r]);
}

// ---- bf16 GEMM, BK=64, K=768 (12 iters), conflict-free XOR swizzle ---------
// EPI==0: 128x96 tile; A async from Xb; scatter Q(prescaled),K,V^T f16 +bias.
// EPI==1: 64x64 tile; A staged from 4 bf16 attention partials + 1/l scaling
//         (A param = partials base, Sm = denominators); out f32 = acc + bias.
template <int EPI>
__global__ __launch_bounds__(256) void k_gemm_bt(
    const __hip_bfloat16* __restrict__ A, const __hip_bfloat16* __restrict__ Bt,
    const float* __restrict__ bias, const float* __restrict__ Sm,
    float* __restrict__ outF,
    _Float16* __restrict__ Qb, _Float16* __restrict__ Kb,
    _Float16* __restrict__ VT) {
  constexpr int BM = (EPI == 0) ? 128 : 64;
  constexpr int BN = (EPI == 0) ? 96 : 64;
  constexpr int MT = BM / 32;  // 16-tiles per wave (m)
  constexpr int NT = BN / 32;  // 16-tiles per wave (n)
  __shared__ __align__(16) __hip_bfloat16 At[BM * 64];
  __shared__ __align__(16) __hip_bfloat16 Btl[BN * 64];
  const int tid = threadIdx.x;
  const int w = tid >> 6, l = tid & 63;
  const int quad = l >> 4, lane16 = l & 15;
  const int m0 = blockIdx.x * BM, n0 = blockIdx.y * BN;

  float4v acc[MT][NT];
#pragma unroll
  for (int i = 0; i < MT; i++)
#pragma unroll
    for (int j = 0; j < NT; j++) acc[i][j] = float4v{0.f, 0.f, 0.f, 0.f};

  const int srow = tid >> 3;
  const int gsrc = (tid & 7) ^ (srow & 7);  // source granule (xor-swizzled)
  const __hip_bfloat16* Asrc = A + (long long)(m0 + srow) * 768 + gsrc * 8;
  const __hip_bfloat16* Bsrc = Bt + (long long)(n0 + srow) * 768 + gsrc * 8;
  __hip_bfloat16* Adst = At + tid * 8;
  __hip_bfloat16* Bdst = Btl + tid * 8;

  const int wr = (w >> 1) * (BM / 2), wc = (w & 1) * (BN / 2);
  const int swz = lane16 & 7;

  for (int kt = 0; kt < 12; kt++) {
    const int k0 = kt * 64;
    __syncthreads();
    if (EPI == 0) {
#pragma unroll
      for (int c = 0; c < BM / 32; c++)
        async_copy16(Asrc + (long long)c * 32 * 768 + k0, Adst + c * 2048);
    } else {
      // fused combine: A = (sum_z Op_z) * (1 / sum_z l_z); head index == kt
#pragma unroll
      for (int c = 0; c < BM / 32; c++) {
        const int m = m0 + c * 32 + srow;
        const int bh = (m >> 11) * 12 + kt;
        const int si = m & 2047;
        float den = Sm[bh * 2048 + si] + Sm[49152 + bh * 2048 + si] +
                    Sm[2 * 49152 + bh * 2048 + si] + Sm[3 * 49152 + bh * 2048 + si];
        const float inv = __builtin_amdgcn_rcpf(den);
        const unsigned short* ap =
            (const unsigned short*)A + (long long)m * 768 + k0 + gsrc * 8;
        ushort8v p0 = *(const ushort8v*)(ap);
        ushort8v p1 = *(const ushort8v*)(ap + 4096ull * 768);
        ushort8v p2 = *(const ushort8v*)(ap + 2ull * 4096 * 768);
        ushort8v p3 = *(const ushort8v*)(ap + 3ull * 4096 * 768);
        ushort8v o;
#pragma unroll
        for (int e = 0; e < 8; e++)
          o[e] = f2bf((bf2f(p0[e]) + bf2f(p1[e]) + bf2f(p2[e]) + bf2f(p3[e])) * inv);
        *(ushort8v*)((unsigned short*)At + c * 2048 + tid * 8) = o;
      }
    }
#pragma unroll
    for (int c = 0; c < BN / 32; c++)
      async_copy16(Bsrc + (long long)c * 32 * 768 + k0, Bdst + c * 2048);
    __syncthreads();
#pragma unroll
    for (int h = 0; h < 2; h++) {
      short8 af[MT], bf[NT];
#pragma unroll
      for (int t = 0; t < MT; t++)
        af[t] = *(const short8*)(At + (wr + t * 16 + lane16) * 64 +
                                 (((h * 4 + quad) ^ swz) * 8));
#pragma unroll
      for (int t = 0; t < NT; t++)
        bf[t] = *(const short8*)(Btl + (wc + t * 16 + lane16) * 64 +
                                 (((h * 4 + quad) ^ swz) * 8));
#pragma unroll
      for (int i = 0; i < MT; i++)
#pragma unroll
        for (int j = 0; j < NT; j++)
          acc[i][j] = __builtin_amdgcn_mfma_f32_16x16x32_bf16(af[i], bf[j], acc[i][j], 0, 0, 0);
    }
  }

  // epilogue: C/D layout col=lane16, row=quad*4+reg
#pragma unroll
  for (int i = 0; i < MT; i++) {
    const int mbase = m0 + wr + i * 16 + quad * 4;
#pragma unroll
    for (int j = 0; j < NT; j++) {
      const int n = n0 + wc + j * 16 + lane16;
      const float bv = bias[n];
      if (EPI == 0) {
        const int which = n / 768;  // uniform across the 16-lane tile
        const int rr = n - which * 768;
        const int hh = rr >> 6, dh = rr & 63;
        const float scale = (which == 0) ? LOG2E_8 : 1.0f;
#pragma unroll
        for (int r = 0; r < 4; r++) {
          const int mm = mbase + r;
          const int b = mm >> 11, s = mm & 2047;
          _Float16 val = (_Float16)((acc[i][j][r] + bv) * scale);
          if (which == 0)
            Qb[((long long)(b * 12 + hh) * 2048 + s) * 64 + dh] = val;
          else if (which == 1)
            Kb[((long long)(b * 12 + hh) * 2048 + s) * 64 + dh] = val;
          else
            VT[((long long)(b * 12 + hh) * 64 + dh) * 2048 + s] = val;
        }
      } else {
#pragma unroll
        for (int r = 0; r < 4; r++)
          outF[(long long)(mbase + r) * 768 + n] = acc[i][j][r] + bv;
      }
    }
  }
}

// ---- attention: 32 q/wave, f16, S^T form, key-split x4, 128-key tiles ------
// grid (S/128, B*H, 4). 4 waves x 32 q = 128 q-rows; 512 keys each (4 iters).
// Per-16-key inner block keeps s/pf liveness ~8 regs; ones-MFMA denominator.
__global__ __launch_bounds__(256, 4) void k_attn(
    const _Float16* __restrict__ Qb, const _Float16* __restrict__ Kb,
    const _Float16* __restrict__ VT, unsigned short* __restrict__ Op,
    float* __restrict__ Sm) {
  __shared__ __align__(16) _Float16 Kl[128 * 64];  // [key][dh], slot g^(r&7)
  __shared__ __align__(16) _Float16 Vl[64 * 128];  // [dh][key], slot g^(r&15)
  const int tid = threadIdx.x, w = tid >> 6, l = tid & 63;
  const int quad = l >> 4, lane16 = l & 15;
  const int bh = blockIdx.y, z = blockIdx.z;
  const int q0w = blockIdx.x * 128 + w * 32;
  const _Float16* Qp = Qb + (long long)bh * 2048 * 64;
  const _Float16* Kp = Kb + (long long)bh * 2048 * 64;
  const _Float16* Vp = VT + (long long)bh * 64 * 2048;

  // Q as B-frags of S^T: B[n=q=lane16][k=dh=quad*8+j], 2 q-groups x 2 k-halves
  half8 qf[2][2];
#pragma unroll
  for (int g = 0; g < 2; g++)
#pragma unroll
    for (int hh = 0; hh < 2; hh++)
      qf[g][hh] = *(const half8*)(Qp + (q0w + g * 16 + lane16) * 64 + hh * 32 + quad * 8);

  float4v o_acc[2][4];  // O^T[dh=dt*16+quad*4+r][q(group g)=lane16]
#pragma unroll
  for (int g = 0; g < 2; g++)
#pragma unroll
    for (int t = 0; t < 4; t++) o_acc[g][t] = float4v{0.f, 0.f, 0.f, 0.f};
  float4v sum_acc[2] = {float4v{0.f, 0.f, 0.f, 0.f}, float4v{0.f, 0.f, 0.f, 0.f}};
  const half4 ones = {(_Float16)1.f, (_Float16)1.f, (_Float16)1.f, (_Float16)1.f};

  const int swz = lane16 & 7;

  for (int kt = 0; kt < 4; kt++) {
    __syncthreads();
    // stage K: 128 rows x 8 granules; slot g^(row&7)
#pragma unroll
    for (int c = 0; c < 4; c++) {
      const int G = c * 256 + tid;
      const int row = G >> 3, src = (G & 7) ^ ((G >> 3) & 7);
      async_copy16(Kp + (long long)(z * 512 + kt * 128 + row) * 64 + src * 8,
                   (_Float16*)Kl + (long long)G * 8);
    }
    // stage V: 64 dh-rows x 16 granules; slot g^(row&15)
#pragma unroll
    for (int c = 0; c < 4; c++) {
      const int G = c * 256 + tid;
      const int row = G >> 4, src = (G & 15) ^ ((G >> 4) & 15);
      async_copy16(Vp + (long long)row * 2048 + z * 512 + kt * 128 + src * 8,
                   (_Float16*)Vl + (long long)G * 8);
    }
    __syncthreads();

#pragma unroll
    for (int kb = 0; kb < 8; kb++) {
      // S^T = K Q^T for this 16-key block; each K-frag feeds both q-groups
      const _Float16* kr = Kl + (kb * 16 + lane16) * 64;
      half8 kf0 = *(const half8*)(kr + ((quad ^ swz) * 8));
      half8 kf1 = *(const half8*)(kr + (((4 + quad) ^ swz) * 8));
      half4 pf[2];
#pragma unroll
      for (int g = 0; g < 2; g++) {
        float4v zz = float4v{0.f, 0.f, 0.f, 0.f};
        zz = __builtin_amdgcn_mfma_f32_16x16x32_f16(kf0, qf[g][0], zz, 0, 0, 0);
        zz = __builtin_amdgcn_mfma_f32_16x16x32_f16(kf1, qf[g][1], zz, 0, 0, 0);
        float p0 = fast_exp2(zz[0]);
        float p1 = fast_exp2(zz[1]);
        float p2 = fast_exp2(zz[2]);
        float p3 = fast_exp2(zz[3]);
        auto lo = __builtin_amdgcn_cvt_pkrtz(p0, p1);
        auto hi = __builtin_amdgcn_cvt_pkrtz(p2, p3);
        pf[g] = half4{static_cast<_Float16>(lo[0]), static_cast<_Float16>(lo[1]),
                      static_cast<_Float16>(hi[0]), static_cast<_Float16>(hi[1])};
        sum_acc[g] = __builtin_amdgcn_mfma_f32_16x16x16f16(ones, pf[g], sum_acc[g], 0, 0, 0);
      }
      // O^T += V^T P^T for this key block; V-frag feeds both q-groups
#pragma unroll
      for (int dt = 0; dt < 4; dt++) {
        const _Float16* vr = Vl + (dt * 16 + lane16) * 128;
        const int g16 = kb * 2 + (quad >> 1);
        half4 vf = *(const half4*)(vr + ((g16 ^ lane16) * 8) + (quad & 1) * 4);
#pragma unroll
        for (int g = 0; g < 2; g++)
          o_acc[g][dt] = __builtin_amdgcn_mfma_f32_16x16x16f16(vf, pf[g], o_acc[g][dt], 0, 0, 0);
      }
    }
  }
  // write bf16 partials; every lane holds the partial denom for its q
  const int b = bh / 12, hd = bh - (bh / 12) * 12;
#pragma unroll
  for (int g = 0; g < 2; g++) {
    const int qrow = q0w + g * 16 + lane16;
    unsigned short* op = Op + (long long)z * 4096 * 768 +
                         ((long long)b * 2048 + qrow) * 768 + hd * 64 + quad * 4;
#pragma unroll
    for (int dt = 0; dt < 4; dt++) {
      ushort4v cv;
#pragma unroll
      for (int r = 0; r < 4; r++) cv[r] = f2bf(o_acc[g][dt][r]);
      *(ushort4v*)(op + dt * 16) = cv;
    }
    if (quad == 0)
      Sm[(long long)z * 49152 + bh * 2048 + qrow] = sum_acc[g][0];
  }
}

extern "C" void kernel_launch(void* const* d_in, const int* in_sizes, int n_in,
                              void* d_out, int out_size, void* d_ws, size_t ws_size,
                              hipStream_t stream) {
  const float* x = (const float*)d_in[0];
  // d_in[1] attention_mask: masks scaled by +1e-9 -> no-op, dropped
  const float* w_qkv = (const float*)d_in[2];
  const float* b_qkv = (const float*)d_in[3];
  const float* w_proj = (const float*)d_in[4];
  const float* b_proj = (const float*)d_in[5];
  float* out = (float*)d_out;

  char* ws = (char*)d_ws;
  size_t off = 0;
  auto alloc = [&](size_t bytes) {
    void* p = ws + off;
    off += (bytes + 255) & ~(size_t)255;
    return p;
  };
  __hip_bfloat16* Xb = (__hip_bfloat16*)alloc(4096ull * 768 * 2);      // 6.3 MB
  __hip_bfloat16* WqkvT = (__hip_bfloat16*)alloc(2304ull * 768 * 2);   // 3.5 MB
  __hip_bfloat16* WprojT = (__hip_bfloat16*)alloc(768ull * 768 * 2);   // 1.2 MB
  _Float16* Qb = (_Float16*)alloc(3145728ull * 2);                     // 6.3 MB
  _Float16* Kb = (_Float16*)alloc(3145728ull * 2);                     // 6.3 MB
  _Float16* VT = (_Float16*)alloc(3145728ull * 2);                     // 6.3 MB
  unsigned short* Opb = (unsigned short*)alloc(4ull * 4096 * 768 * 2); // 25.2 MB
  float* Sm = (float*)alloc(4ull * 24 * 2048 * 4);                     // 0.8 MB

  k_prep<<<5376, 256, 0, stream>>>(x, (unsigned short*)Xb, w_qkv, WqkvT,
                                   w_proj, WprojT);
  k_gemm_bt<0><<<dim3(32, 24), 256, 0, stream>>>(Xb, WqkvT, b_qkv, nullptr,
                                                 nullptr, Qb, Kb, VT);
  k_attn<<<dim3(16, 24, 4), 256, 0, stream>>>(Qb, Kb, VT, Opb, Sm);
  k_gemm_bt<1><<<dim3(64, 12), 256, 0, stream>>>((const __hip_bfloat16*)Opb,
                                                 WprojT, b_proj, Sm, out,
                                                 nullptr, nullptr, nullptr);
}